// Round 4
// baseline (66.156 us; speedup 1.0000x reference)
//
#include <hip/hip_runtime.h>

// ShiftMap fused, v4:
//  - kernel 1: x-interpolate the 16x16 control grid to Xsc[b][16][1024] (float2,
//    pre-scaled by (H-1)/2,(W-1)/2) in d_ws — each value reused 256x by kernel 2.
//  - kernel 2: per pixel only y-interp (4 coalesced float2 loads + 8 FMA, wy
//    uniform per row) + 4x4 gather (all 16 loads clustered, interior fast path).
//  - XCD-aware swizzle keeps each batch's 4MB image in one XCD's L2.

static constexpr float A = -0.75f;  // PyTorch bicubic coefficient
static constexpr int NXCD = 8;

__device__ __forceinline__ void cubic_weights(float t, float* w) {
    float t2 = t * t;
    float s  = 1.0f - t;
    w[1] = (A + 2.0f) * t * t2 - (A + 3.0f) * t2 + 1.0f;       // dist = t
    w[2] = (A + 2.0f) * s * s * s - (A + 3.0f) * s * s + 1.0f; // dist = 1-t
    float u = 1.0f + t;
    w[0] = A * (u * (u * (u - 5.0f) + 8.0f) - 4.0f);           // dist = 1+t
    float v = 2.0f - t;
    w[3] = A * (v * (v * (v - 5.0f) + 8.0f) - 4.0f);           // dist = 2-t
}

// ---- kernel 1: Xsc[b][cy][x] = (smy(x)*half_h, smx(x)*half_w) ----
__global__ __launch_bounds__(256) void xinterp_kernel(
    const float* __restrict__ smap,  // (B,CH,CW,2)
    float2* __restrict__ xsc,        // (B,CH,W)
    int W, int CH, int CW, float scale_x, float half_h, float half_w)
{
    const int x  = blockIdx.x * 256 + threadIdx.x;
    const int cy = blockIdx.y;
    const int b  = blockIdx.z;
    if (x >= W) return;

    const float sx  = x * scale_x;
    const float fx0 = floorf(sx);
    const int   cx0 = (int)fx0;
    float wx[4];
    cubic_weights(sx - fx0, wx);

    const float* row = smap + (((size_t)b * CH + cy) * CW) * 2;
    float vy = 0.0f, vx = 0.0f;
    #pragma unroll
    for (int j = 0; j < 4; ++j) {
        const int cx = min(max(cx0 - 1 + j, 0), CW - 1);
        vy += wx[j] * row[cx * 2 + 0];
        vx += wx[j] * row[cx * 2 + 1];
    }
    xsc[((size_t)b * CH + cy) * W + x] = make_float2(vy * half_h, vx * half_w);
}

// ---- kernel 2: warp ----
template <int PX_PER_THREAD>
__global__ __launch_bounds__(256) void shiftmap_warp_kernel(
    const float* __restrict__ img,    // (B,1,H,W)
    const float2* __restrict__ xsc,   // (B,CH,W)
    float* __restrict__ out,          // (B,1,H,W)
    int H, int W, int CH, int nblocks, float scale_y)
{
    // XCD-aware swizzle: dispatch d lands on XCD d%8 -> contiguous work band.
    const int d    = blockIdx.x;
    const int per  = nblocks / NXCD;
    const int work = (d % NXCD) * per + d / NXCD;
    const int y = work % H;
    const int b = work / H;
    const int tid = threadIdx.x;

    // row-uniform y-interp weights + clamped control-row base pointers
    const float sy  = y * scale_y;
    const float fy0 = floorf(sy);
    const int   cy0 = (int)fy0;
    float wy[4];
    cubic_weights(sy - fy0, wy);
    const float2* bp0 = xsc + ((size_t)b * CH + min(max(cy0 - 1, 0), CH - 1)) * W;
    const float2* bp1 = xsc + ((size_t)b * CH + min(max(cy0    , 0), CH - 1)) * W;
    const float2* bp2 = xsc + ((size_t)b * CH + min(max(cy0 + 1, 0), CH - 1)) * W;
    const float2* bp3 = xsc + ((size_t)b * CH + min(max(cy0 + 2, 0), CH - 1)) * W;

    const float* imgb = img + (size_t)b * H * W;
    float* outb = out + (size_t)b * H * W + (size_t)y * W;

    #pragma unroll
    for (int k = 0; k < PX_PER_THREAD; ++k) {
        const int x = tid + k * 256;

        // ---- y-interp of precomputed x-interpolated control rows ----
        const float2 c0 = bp0[x], c1 = bp1[x], c2 = bp2[x], c3 = bp3[x];
        const float smy = wy[0] * c0.x + wy[1] * c1.x + wy[2] * c2.x + wy[3] * c3.x;
        const float smx = wy[0] * c0.y + wy[1] * c1.y + wy[2] * c2.y + wy[3] * c3.y;

        // ---- sampling coords (mesh folded analytically, scales pre-applied) ----
        const float ix = (float)x + smx;
        const float iy = (float)y + smy;
        const float ixf = floorf(ix), iyf = floorf(iy);
        const int ix0 = (int)ixf, iy0 = (int)iyf;
        float gwx[4], gwy[4];
        cubic_weights(ix - ixf, gwx);
        cubic_weights(iy - iyf, gwy);

        // ---- 4x4 bicubic gather ----
        float acc = 0.0f;
        if (ix0 >= 1 && ix0 <= W - 3 && iy0 >= 1 && iy0 <= H - 3) {
            // interior: cluster all 16 loads, then FMA
            const float* p = imgb + (size_t)(iy0 - 1) * W + (ix0 - 1);
            float f[4][4];
            #pragma unroll
            for (int i = 0; i < 4; ++i) {
                f[i][0] = p[0]; f[i][1] = p[1]; f[i][2] = p[2]; f[i][3] = p[3];
                p += W;
            }
            #pragma unroll
            for (int i = 0; i < 4; ++i) {
                acc += gwy[i] * (gwx[0] * f[i][0] + gwx[1] * f[i][1]
                               + gwx[2] * f[i][2] + gwx[3] * f[i][3]);
            }
        } else {
            // border: zeros padding with per-tap masks
            #pragma unroll
            for (int i = 0; i < 4; ++i) {
                const int yy = iy0 - 1 + i;
                const bool vy = (yy >= 0) && (yy < H);
                const int yc = min(max(yy, 0), H - 1);
                const float* row = imgb + (size_t)yc * W;
                float r = 0.0f;
                #pragma unroll
                for (int j = 0; j < 4; ++j) {
                    const int xx = ix0 - 1 + j;
                    const bool v = vy && (xx >= 0) && (xx < W);
                    const int xc = min(max(xx, 0), W - 1);
                    r += gwx[j] * (v ? row[xc] : 0.0f);
                }
                acc += gwy[i] * r;
            }
        }
        outb[x] = acc;
    }
}

// ---- fallback (v3 single-kernel) if ws_size is too small ----
template <int PX_PER_THREAD>
__global__ __launch_bounds__(256) void shiftmap_warp_fallback(
    const float* __restrict__ img, const float* __restrict__ smap,
    float* __restrict__ out, int H, int W, int CH, int CW, int nblocks)
{
    const int d   = blockIdx.x;
    const int per = nblocks / NXCD;
    const int work = (d % NXCD) * per + d / NXCD;
    const int y = work % H;
    const int b = work / H;
    const int tid = threadIdx.x;

    __shared__ float s_row[64];
    const float scale_y = (float)((double)(CH - 1) / (double)(H - 1));
    const float scale_x = (float)((double)(CW - 1) / (double)(W - 1));

    if (tid < CW * 2) {
        const int c = tid >> 1, ch = tid & 1;
        const float sy = y * scale_y;
        const float fy0 = floorf(sy);
        const int cy0 = (int)fy0;
        float wy[4];
        cubic_weights(sy - fy0, wy);
        float v = 0.0f;
        #pragma unroll
        for (int i = 0; i < 4; ++i) {
            const int cy = min(max(cy0 - 1 + i, 0), CH - 1);
            v += wy[i] * smap[(((size_t)b * CH + cy) * CW + c) * 2 + ch];
        }
        s_row[tid] = v;
    }
    __syncthreads();

    const float half_w = 0.5f * (float)(W - 1);
    const float half_h = 0.5f * (float)(H - 1);
    const float* imgb = img + (size_t)b * H * W;
    float* outb = out + (size_t)b * H * W + (size_t)y * W;

    #pragma unroll
    for (int k = 0; k < PX_PER_THREAD; ++k) {
        const int x = tid + k * 256;
        const float sx = x * scale_x;
        const float fx0 = floorf(sx);
        const int cx0 = (int)fx0;
        float wx[4];
        cubic_weights(sx - fx0, wx);
        float smy = 0.0f, smx = 0.0f;
        #pragma unroll
        for (int j = 0; j < 4; ++j) {
            const int cx = min(max(cx0 - 1 + j, 0), CW - 1);
            smy += wx[j] * s_row[cx * 2 + 0];
            smx += wx[j] * s_row[cx * 2 + 1];
        }
        const float ix = (float)x + smx * half_w;
        const float iy = (float)y + smy * half_h;
        const float ixf = floorf(ix), iyf = floorf(iy);
        const int ix0 = (int)ixf, iy0 = (int)iyf;
        float gwx[4], gwy[4];
        cubic_weights(ix - ixf, gwx);
        cubic_weights(iy - iyf, gwy);
        float acc = 0.0f;
        #pragma unroll
        for (int i = 0; i < 4; ++i) {
            const int yy = iy0 - 1 + i;
            const bool vy = (yy >= 0) && (yy < H);
            const int yc = min(max(yy, 0), H - 1);
            const float* row = imgb + (size_t)yc * W;
            float r = 0.0f;
            #pragma unroll
            for (int j = 0; j < 4; ++j) {
                const int xx = ix0 - 1 + j;
                const bool v = vy && (xx >= 0) && (xx < W);
                const int xc = min(max(xx, 0), W - 1);
                r += gwx[j] * (v ? row[xc] : 0.0f);
            }
            acc += gwy[i] * r;
        }
        outb[x] = acc;
    }
}

extern "C" void kernel_launch(void* const* d_in, const int* in_sizes, int n_in,
                              void* d_out, int out_size, void* d_ws, size_t ws_size,
                              hipStream_t stream) {
    const float* img  = (const float*)d_in[0];  // (B,1,1024,1024) fp32
    const float* smap = (const float*)d_in[1];  // (B,16,16,2) fp32
    float* out = (float*)d_out;

    const int H = 1024, W = 1024;
    const int CH = 16, CW = 16;
    const int B = in_sizes[0] / (H * W);
    const int nblocks = H * B;

    const float scale_y = (float)((double)(CH - 1) / (double)(H - 1));
    const float scale_x = (float)((double)(CW - 1) / (double)(W - 1));
    const float half_h = 0.5f * (float)(H - 1);
    const float half_w = 0.5f * (float)(W - 1);

    const size_t ws_needed = (size_t)B * CH * W * sizeof(float2);
    if (ws_size >= ws_needed) {
        float2* xsc = (float2*)d_ws;
        dim3 g1(W / 256, CH, B);
        xinterp_kernel<<<g1, 256, 0, stream>>>(smap, xsc, W, CH, CW,
                                               scale_x, half_h, half_w);
        dim3 g2(nblocks);
        shiftmap_warp_kernel<4><<<g2, 256, 0, stream>>>(img, xsc, out,
                                                        H, W, CH, nblocks, scale_y);
    } else {
        dim3 g2(nblocks);
        shiftmap_warp_fallback<4><<<g2, 256, 0, stream>>>(img, smap, out,
                                                          H, W, CH, CW, nblocks);
    }
}